// Round 6
// baseline (639.429 us; speedup 1.0000x reference)
//
#include <hip/hip_runtime.h>

#define N_PTS 32768
#define HID   100
#define STEPS 100
#define NPAIR 52   // hidden padded 100 -> 104, stored as 52 (j,j+1) pairs
#define LPP   13   // pairs per lane (4 lanes/point * 13 pairs * 2 j = 104)
#define RPP   20   // b128 rows per pair record (320 B)

// Output layout (concatenated flat, fp32):
#define OFF_Z     0
#define OFF_MUXZ  65536
#define OFF_LSXZ  163840
#define OFF_MUZX  262144
#define OFF_LTZX  327680
#define OFF_MUZ   360448
#define OFF_LTZ   425984

typedef float v2f __attribute__((ext_vector_type(2)));
typedef float v4f __attribute__((ext_vector_type(4)));

#if __has_builtin(__builtin_elementwise_fma)
#define FMA2(a, b, c) __builtin_elementwise_fma((a), (b), (c))
#else
#define FMA2(a, b, c) ((a) * (b) + (c))
#endif
#define LOv(q) __builtin_shufflevector((q), (q), 0, 1)
#define HIv(q) __builtin_shufflevector((q), (q), 2, 3)

__device__ __forceinline__ v2f splat(float x) { v2f r; r.x = x; r.y = x; return r; }

// Butterfly sum across a quad of lanes via DPP quad_perm (xor1=0xB1, xor2=0x4E).
__device__ __forceinline__ float qreduce(float v) {
  v += __int_as_float(__builtin_amdgcn_update_dpp(0, __float_as_int(v), 0xB1, 0xF, 0xF, true));
  v += __int_as_float(__builtin_amdgcn_update_dpp(0, __float_as_int(v), 0x4E, 0xF, 0xF, true));
  return v;
}
// horizontal (even/odd j partials) then quad reduce
__device__ __forceinline__ float hqreduce(v2f v) { return qreduce(v.x + v.y); }

// ---------------- Encoder chunk: x -> h1 -> h2 partial -> (m0,m1,lt) ----------
template<int NP>
__device__ __forceinline__ void enc_chunk(
    int ob, float x0, float x1, float x2,
    const float* __restrict__ We1, const float* __restrict__ be1,
    const float* __restrict__ We2, const float* __restrict__ be2,
    const float* __restrict__ Wmu, const float* __restrict__ Wlt,
    float& m0, float& m1, float& lt)
{
  v2f acc2[NP];
  #pragma unroll
  for (int i = 0; i < NP; ++i) acc2[i] = splat(0.f);

  #pragma unroll 2
  for (int k = 0; k < HID; k += 2) {
    const v2f w0 = *(const v2f*)(We1 + k);
    const v2f w1 = *(const v2f*)(We1 + HID + k);
    const v2f w2 = *(const v2f*)(We1 + 2*HID + k);
    const v2f bb = *(const v2f*)(be1 + k);
    v2f aP = FMA2(splat(x0), w0, FMA2(splat(x1), w1, FMA2(splat(x2), w2, bb)));
    const float e0 = __expf(-aP.x), e1 = __expf(-aP.y);
    const float s0 = 1.f / (1.f + e0), s1 = 1.f / (1.f + e1);
    const v2f hh0 = splat(aP.x * s0);
    const v2f hh1 = splat(aP.y * s1);
    const v2f* r0 = (const v2f*)(We2 + k*HID + ob);        // 8B-aligned (even)
    const v2f* r1 = (const v2f*)(We2 + (k+1)*HID + ob);
    #pragma unroll
    for (int oo = 0; oo < NP; ++oo) {
      v2f tacc = FMA2(hh0, r0[oo], acc2[oo]);   // k then k+1: baseline order
      acc2[oo] = FMA2(hh1, r1[oo], tacc);
    }
  }

  m0 = 0.f; m1 = 0.f; lt = 0.f;
  #pragma unroll
  for (int oo = 0; oo < NP; ++oo) {
    #pragma unroll
    for (int h = 0; h < 2; ++h) {
      const int o = ob + 2*oo + h;
      float a   = (h ? acc2[oo].y : acc2[oo].x) + be2[o];
      float sig = 1.f / (1.f + __expf(-a));
      float h2  = a * sig;
      m0 = fmaf(h2, Wmu[o*2+0], m0);
      m1 = fmaf(h2, Wmu[o*2+1], m1);
      lt = fmaf(h2, Wlt[o],     lt);
    }
  }
}

// ---------------- Fused kernel: encoder -> SDE -> final decode ----------------
// SDE record per pair = 20 b128 rows (320 B), all STEP-INVARIANT weight
// products precomputed at fill time so the j-loop multiplies only by u / u2
// (removes the per-step c0,c1,q00,q01,q11 rebuild: -5 v_pk ops/pair = -12% of
// VALU cycles; v_pk saves issue slots but costs full 2x fp32 datapath passes,
// so only deleted ops save time). Row layout (pairs are {j0,j1}):
//   R0 : {W0, W1}            R1 : {b, Jw0}
//   R2..R7  : Jw1..Jw11, Kw0    (Jw[k]: k&1->W1 else W0; (k>>1)&1->s else m; o=k>>2)
//   R7.hi..R16.lo : Kw0..Kw17   (Kw[k]: o=k/6, ms=(k%6)/3, c=k%3: {W00,W01,W11})
//   R16.hi : pad
//   R17..R19 : {m_o, s_o} pairs (final decode only)
// CRITICAL: pair loop stays ROLLED (#pragma unroll 2, loop-carried pointer).
// Full unroll makes the ds_reads step-loop-invariant -> LICM hoists ~LDS into
// registers -> scratch spill (round-1: FETCH 13MB -> 4.13GB, VALUBusy 78->25).
__global__ __launch_bounds__(256, 2) void vaebm_kernel(
    const float* __restrict__ x,
    const float* __restrict__ We1, const float* __restrict__ be1,
    const float* __restrict__ We2, const float* __restrict__ be2,
    const float* __restrict__ Wmu, const float* __restrict__ bmu,
    const float* __restrict__ Wlt, const float* __restrict__ blt,
    const float* __restrict__ Wd1,  const float* __restrict__ bd1,
    const float* __restrict__ Wdmu, const float* __restrict__ bdmu,
    const float* __restrict__ Wds,  const float* __restrict__ bds,
    const float* __restrict__ b_muz, const float* __restrict__ b_ltz,
    const float* __restrict__ noise,
    float* __restrict__ out)
{
  __shared__ __align__(16) float wrec[NPAIR * RPP * 4];
  __shared__ float red[4][64][3];
  __shared__ float zlds[64][3];

  const int tid = threadIdx.x;

  // ---- SDE weight-record fill (runs once; divergence is fine) ----
  for (int idx = tid; idx < NPAIR * RPP * 4; idx += 256) {
    const int pr = idx / (RPP*4), f = idx - pr * (RPP*4);
    const int par = f & 1, g = f >> 1;
    const int j = pr * 2 + par;
    float v = 0.f;
    if (j < HID && g != 33) {
      const float w0 = Wd1[j], w1 = Wd1[HID + j];
      if      (g == 0) v = w0;
      else if (g == 1) v = w1;
      else if (g == 2) v = bd1[j];
      else if (g < 15) {                 // Jw[k], k = g-3
        const int k = g - 3, o = k >> 2;
        const float ws = (k & 1) ? w1 : w0;
        const float ms = ((k >> 1) & 1) ? Wds[j*3+o] : Wdmu[j*3+o];
        v = ws * ms;
      } else if (g < 33) {               // Kw[k], k = g-15
        const int k = g - 15, o = k / 6, r = k - o*6;
        const int msf = r / 3, c = r - msf*3;
        const float wq = (c == 0) ? w0*w0 : (c == 1) ? w0*w1 : w1*w1;
        const float ms = msf ? Wds[j*3+o] : Wdmu[j*3+o];
        v = wq * ms;
      } else if (g >= 34) {              // ms[g-34] = [m0,s0,m1,s1,m2,s2]
        const int k = g - 34, o = k >> 1;
        v = (k & 1) ? Wds[j*3+o] : Wdmu[j*3+o];
      }
    }
    wrec[idx] = v;
  }

  // ---- Phase 1: encoder ----
  const int w  = tid >> 6;            // wave 0..3
  const int pb = tid & 63;            // point within block
  const int p  = blockIdx.x * 64 + pb;

  const float x0 = x[p*3+0], x1 = x[p*3+1], x2 = x[p*3+2];

  float m0, m1, lt;
  if (w < 2) enc_chunk<13>(w * 26,            x0, x1, x2, We1, be1, We2, be2, Wmu, Wlt, m0, m1, lt);
  else       enc_chunk<12>(52 + (w - 2) * 24, x0, x1, x2, We1, be1, We2, be2, Wmu, Wlt, m0, m1, lt);

  red[w][pb][0] = m0; red[w][pb][1] = m1; red[w][pb][2] = lt;
  __syncthreads();
  if (w == 0) {
    m0 += red[1][pb][0] + red[2][pb][0] + red[3][pb][0] + bmu[0];
    m1 += red[1][pb][1] + red[2][pb][1] + red[3][pb][1] + bmu[1];
    lt += red[1][pb][2] + red[2][pb][2] + red[3][pb][2] + blt[0];
    out[OFF_MUZX + p*2+0] = m0;
    out[OFF_MUZX + p*2+1] = m1;
    out[OFF_LTZX + p]     = lt;
    out[OFF_MUZ  + p*2+0] = b_muz[0];
    out[OFF_MUZ  + p*2+1] = b_muz[1];
    out[OFF_LTZ  + p]     = b_ltz[0];
    zlds[pb][0] = m0; zlds[pb][1] = m1; zlds[pb][2] = lt;
  }
  __syncthreads();

  // ---- Phase 2: SDE (100 Euler-Maruyama steps on the pullback metric) ----
  const int l     = tid & 3;                    // lane within quad
  const int pt    = tid >> 2;                   // point within block
  const int pg    = blockIdx.x * 64 + pt;       // global point
  const int pbase = l * LPP;                    // lane's first pair
  const v4f* __restrict__ Rq = (const v4f*)wrec;   // RPP v4f per pair

  float z0 = zlds[pt][0];
  float z1 = zlds[pt][1];
  const float sdt = __expf(zlds[pt][2]) * 0.1f;  // sqrt(dt) = exp(lt)/sqrt(100)

  const float2* __restrict__ noise2 = (const float2*)noise;

  for (int step = 0; step < STEPS; ++step) {
    // issue the noise load early; its latency hides under the j-loop
    const float2 nz = noise2[(size_t)step * N_PTS + pg];

    v2f Jm[3][2], Js[3][2], Km[3][3], Ks[3][3];
    #pragma unroll
    for (int o = 0; o < 3; ++o) {
      Jm[o][0]=splat(0.f); Jm[o][1]=splat(0.f);
      Js[o][0]=splat(0.f); Js[o][1]=splat(0.f);
      Km[o][0]=splat(0.f); Km[o][1]=splat(0.f); Km[o][2]=splat(0.f);
      Ks[o][0]=splat(0.f); Ks[o][1]=splat(0.f); Ks[o][2]=splat(0.f);
    }
    const v2f z0P = splat(z0), z1P = splat(z1);

    // ROLLED loop (partial unroll) with loop-carried pointer (see header).
    const v4f* R = Rq + pbase * RPP;
    #pragma unroll 2
    for (int t = 0; t < LPP; ++t, R += RPP) {
      const v4f A  = R[0];                    // {W0p, W1p}
      const v4f R1 = R[1];                    // {bp, Jw0}

      v2f aP = FMA2(z0P, LOv(A), FMA2(z1P, HIv(A), LOv(R1)));
      v2f eP;   eP.x   = __expf(-aP.x);               eP.y   = __expf(-aP.y);
      v2f dP = splat(1.f) + eP;
      v2f sigP; sigP.x = __builtin_amdgcn_rcpf(dP.x); sigP.y = __builtin_amdgcn_rcpf(dP.y);
      const v2f ppP  = FMA2(-sigP, sigP, sigP);                 // sig(1-sig)
      const v2f uP   = FMA2(aP, ppP, sigP);                     // swish'
      const v2f w2sP = FMA2(splat(-2.f), sigP, splat(1.f));     // 1-2sig
      const v2f u2P  = FMA2(uP, w2sP, sigP);                    // swish''

      const v4f R2 = R[2],  R3 = R[3],  R4 = R[4],  R5 = R[5];
      const v4f R6 = R[6],  R7 = R[7];
      Jm[0][0] = FMA2(uP, HIv(R1), Jm[0][0]);
      Jm[0][1] = FMA2(uP, LOv(R2), Jm[0][1]);
      Js[0][0] = FMA2(uP, HIv(R2), Js[0][0]);
      Js[0][1] = FMA2(uP, LOv(R3), Js[0][1]);
      Jm[1][0] = FMA2(uP, HIv(R3), Jm[1][0]);
      Jm[1][1] = FMA2(uP, LOv(R4), Jm[1][1]);
      Js[1][0] = FMA2(uP, HIv(R4), Js[1][0]);
      Js[1][1] = FMA2(uP, LOv(R5), Js[1][1]);
      Jm[2][0] = FMA2(uP, HIv(R5), Jm[2][0]);
      Jm[2][1] = FMA2(uP, LOv(R6), Jm[2][1]);
      Js[2][0] = FMA2(uP, HIv(R6), Js[2][0]);
      Js[2][1] = FMA2(uP, LOv(R7), Js[2][1]);

      const v4f R8  = R[8],  R9  = R[9],  R10 = R[10], R11 = R[11];
      const v4f R12 = R[12], R13 = R[13], R14 = R[14], R15 = R[15];
      const v4f R16 = R[16];
      Km[0][0] = FMA2(u2P, HIv(R7),  Km[0][0]);
      Km[0][1] = FMA2(u2P, LOv(R8),  Km[0][1]);
      Km[0][2] = FMA2(u2P, HIv(R8),  Km[0][2]);
      Ks[0][0] = FMA2(u2P, LOv(R9),  Ks[0][0]);
      Ks[0][1] = FMA2(u2P, HIv(R9),  Ks[0][1]);
      Ks[0][2] = FMA2(u2P, LOv(R10), Ks[0][2]);
      Km[1][0] = FMA2(u2P, HIv(R10), Km[1][0]);
      Km[1][1] = FMA2(u2P, LOv(R11), Km[1][1]);
      Km[1][2] = FMA2(u2P, HIv(R11), Km[1][2]);
      Ks[1][0] = FMA2(u2P, LOv(R12), Ks[1][0]);
      Ks[1][1] = FMA2(u2P, HIv(R12), Ks[1][1]);
      Ks[1][2] = FMA2(u2P, LOv(R13), Ks[1][2]);
      Km[2][0] = FMA2(u2P, HIv(R13), Km[2][0]);
      Km[2][1] = FMA2(u2P, LOv(R14), Km[2][1]);
      Km[2][2] = FMA2(u2P, HIv(R14), Km[2][2]);
      Ks[2][0] = FMA2(u2P, LOv(R15), Ks[2][0]);
      Ks[2][1] = FMA2(u2P, HIv(R15), Ks[2][1]);
      Ks[2][2] = FMA2(u2P, LOv(R16), Ks[2][2]);
    }

    // fold even/odd-j partials, then complete the j-sums across the quad
    float JmS[3][2], JsS[3][2], KmS[3][3], KsS[3][3];
    #pragma unroll
    for (int o = 0; o < 3; ++o) {
      JmS[o][0]=hqreduce(Jm[o][0]); JmS[o][1]=hqreduce(Jm[o][1]);
      JsS[o][0]=hqreduce(Js[o][0]); JsS[o][1]=hqreduce(Js[o][1]);
      KmS[o][0]=hqreduce(Km[o][0]); KmS[o][1]=hqreduce(Km[o][1]); KmS[o][2]=hqreduce(Km[o][2]);
      KsS[o][0]=hqreduce(Ks[o][0]); KsS[o][1]=hqreduce(Ks[o][1]); KsS[o][2]=hqreduce(Ks[o][2]);
    }

    // G = J^T J (2x2 sym)
    float G00=0.f, G01=0.f, G11=0.f;
    #pragma unroll
    for (int o = 0; o < 3; ++o) {
      G00 += JmS[o][0]*JmS[o][0] + JsS[o][0]*JsS[o][0];
      G01 += JmS[o][0]*JmS[o][1] + JsS[o][0]*JsS[o][1];
      G11 += JmS[o][1]*JmS[o][1] + JsS[o][1]*JsS[o][1];
    }
    // D[c][l] = dG[km]/dz_l (sym in k,m)
    float D00=0.f, D01=0.f, D10=0.f, D11=0.f, D20=0.f, D21=0.f;
    #pragma unroll
    for (int o = 0; o < 3; ++o) {
      D00 += 2.f*(KmS[o][0]*JmS[o][0] + KsS[o][0]*JsS[o][0]);
      D01 += 2.f*(KmS[o][1]*JmS[o][0] + KsS[o][1]*JsS[o][0]);
      D10 += KmS[o][0]*JmS[o][1] + JmS[o][0]*KmS[o][1] + KsS[o][0]*JsS[o][1] + JsS[o][0]*KsS[o][1];
      D11 += KmS[o][1]*JmS[o][1] + JmS[o][0]*KmS[o][2] + KsS[o][1]*JsS[o][1] + JsS[o][0]*KsS[o][2];
      D20 += 2.f*(KmS[o][1]*JmS[o][1] + KsS[o][1]*JsS[o][1]);
      D21 += 2.f*(KmS[o][2]*JmS[o][1] + KsS[o][2]*JsS[o][1]);
    }
    const float det = fmaf(G00, G11, -G01*G01);
    const float id  = __builtin_amdgcn_rcpf(det);
    const float i00 = G11*id, i01 = -G01*id, i11 = G00*id;
    // drift via S/P contraction (symbolically identical to the T/Chris form)
    const float S0 = fmaf(i00, D00, fmaf(i01, D01 + D10, i11 * D11));
    const float S1 = fmaf(i00, D10, fmaf(i01, D11 + D20, i11 * D21));
    const float i01d = i01 + i01;
    const float P0 = fmaf(i00, D00, fmaf(i01d, D10, i11 * D20));
    const float P1 = fmaf(i00, D01, fmaf(i01d, D11, i11 * D21));
    const float R0 = fmaf(0.5f, S0, -0.25f * P0);
    const float R1v = fmaf(0.5f, S1, -0.25f * P1);
    const float dr0 = fmaf(i00, R0, i01 * R1v);
    const float dr1 = fmaf(i01, R0, i11 * R1v);

    const float dw0 = sdt*nz.x, dw1 = sdt*nz.y;
    z0 += dr0 + i00*dw0 + i01*dw1;   // + ginv @ dW
    z1 += dr1 + i01*dw0 + i11*dw1;
  }

  // ---- final decode on z ----
  v2f MSm[3], MSs[3];
  #pragma unroll
  for (int o = 0; o < 3; ++o) { MSm[o] = splat(0.f); MSs[o] = splat(0.f); }
  const v2f zf0 = splat(z0), zf1 = splat(z1);
  {
    const v4f* R = Rq + pbase * RPP;
    #pragma unroll 2
    for (int t = 0; t < LPP; ++t, R += RPP) {
      const v4f A  = R[0];
      const v2f bP = LOv(R[1]);
      v2f aP = FMA2(zf0, LOv(A), FMA2(zf1, HIv(A), bP));
      v2f eP;   eP.x   = __expf(-aP.x);               eP.y   = __expf(-aP.y);
      v2f dP = splat(1.f) + eP;
      v2f sigP; sigP.x = __builtin_amdgcn_rcpf(dP.x); sigP.y = __builtin_amdgcn_rcpf(dP.y);
      const v2f hP = aP * sigP;
      const v4f R17 = R[17], R18 = R[18], R19 = R[19];
      MSm[0] = FMA2(hP, LOv(R17), MSm[0]);  MSs[0] = FMA2(hP, HIv(R17), MSs[0]);
      MSm[1] = FMA2(hP, LOv(R18), MSm[1]);  MSs[1] = FMA2(hP, HIv(R18), MSs[1]);
      MSm[2] = FMA2(hP, LOv(R19), MSm[2]);  MSs[2] = FMA2(hP, HIv(R19), MSs[2]);
    }
  }
  // reductions must run on all quad lanes (DPP reads masked lanes as 0)
  float mu[3], ls[3];
  #pragma unroll
  for (int o = 0; o < 3; ++o) { mu[o] = hqreduce(MSm[o]); ls[o] = hqreduce(MSs[o]); }

  if (l == 0) {
    out[OFF_Z + pg*2+0] = z0;
    out[OFF_Z + pg*2+1] = z1;
    #pragma unroll
    for (int o = 0; o < 3; ++o) {
      out[OFF_MUXZ + pg*3 + o] = mu[o] + bdmu[o];
      out[OFF_LSXZ + pg*3 + o] = ls[o] + bds[o];
    }
  }
}

extern "C" void kernel_launch(void* const* d_in, const int* in_sizes, int n_in,
                              void* d_out, int out_size, void* d_ws, size_t ws_size,
                              hipStream_t stream) {
  (void)in_sizes; (void)n_in; (void)d_ws; (void)ws_size; (void)out_size;
  const float* x    = (const float*)d_in[0];
  const float* We1  = (const float*)d_in[1];
  const float* be1  = (const float*)d_in[2];
  const float* We2  = (const float*)d_in[3];
  const float* be2  = (const float*)d_in[4];
  const float* Wmu  = (const float*)d_in[5];
  const float* bmu  = (const float*)d_in[6];
  const float* Wlt  = (const float*)d_in[7];
  const float* blt  = (const float*)d_in[8];
  const float* Wd1  = (const float*)d_in[9];
  const float* bd1  = (const float*)d_in[10];
  const float* Wdmu = (const float*)d_in[11];
  const float* bdmu = (const float*)d_in[12];
  const float* Wds  = (const float*)d_in[13];
  const float* bds  = (const float*)d_in[14];
  const float* bmz  = (const float*)d_in[15];
  const float* blz  = (const float*)d_in[16];
  const float* noise= (const float*)d_in[17];
  float* out = (float*)d_out;

  vaebm_kernel<<<512, 256, 0, stream>>>(x, We1, be1, We2, be2, Wmu, bmu, Wlt, blt,
                                        Wd1, bd1, Wdmu, bdmu, Wds, bds,
                                        bmz, blz, noise, out);
}